// Round 7
// baseline (492.199 us; speedup 1.0000x reference)
//
#include <hip/hip_runtime.h>

#define SEQ   2048
#define BATCH 2
#define EMB   512
#define NH    8

typedef short bf16x8 __attribute__((ext_vector_type(8)));
typedef float f32x4  __attribute__((ext_vector_type(4)));
typedef unsigned short u16;
typedef unsigned long long u64;

static __device__ __forceinline__ u16 f2bf(float f) {
    unsigned u = __float_as_uint(f);
    return (u16)((u + 0x7FFF + ((u >> 16) & 1)) >> 16);   // rne
}
static __device__ __forceinline__ float bf2f(u16 h) {
    return __uint_as_float((unsigned)h << 16);
}
static __device__ __forceinline__ unsigned cvtpk(float a, float b) {
    unsigned r;
    asm("v_cvt_pk_bf16_f32 %0, %1, %2" : "=v"(r) : "v"(a), "v"(b));
    return r;   // low16 = bf16(a), high16 = bf16(b), rne
}
// split 8 consecutive f32 into hi/lo bf16x8
static __device__ __forceinline__ void split8(const float* p, bf16x8& hi, bf16x8& lo) {
    const float4 f0 = *(const float4*)p;
    const float4 f1 = *(const float4*)(p + 4);
    const float fv[8] = {f0.x, f0.y, f0.z, f0.w, f1.x, f1.y, f1.z, f1.w};
    union { unsigned w[4]; bf16x8 v; } H, L;
#pragma unroll
    for (int q = 0; q < 4; ++q) {
        const float a = fv[2 * q], b = fv[2 * q + 1];
        const unsigned h = cvtpk(a, b);
        const float la = a - __uint_as_float(h << 16);
        const float lb = b - __uint_as_float(h & 0xFFFF0000u);
        H.w[q] = h;
        L.w[q] = cvtpk(la, lb);
    }
    hi = H.v; lo = L.v;
}

// =====================================================================
// convert_w: split f32 weights -> bf16 hi/lo. 262144 float4 groups.
// =====================================================================
#define IW4 196608
#define W4  262144
__global__ __launch_bounds__(256) void convert_w(
    const float* __restrict__ ipw, const float* __restrict__ opw,
    u16* __restrict__ iwh, u16* __restrict__ iwl,
    u16* __restrict__ owh, u16* __restrict__ owl)
{
    const int f = blockIdx.x * 256 + threadIdx.x;
    if (f >= W4) return;
    const float* src; u16 *dh, *dl; int o;
    if (f < IW4) { src = ipw; dh = iwh; dl = iwl; o = f; }
    else         { src = opw; dh = owh; dl = owl; o = f - IW4; }
    const float4 x = ((const float4*)src)[o];
    ushort4 hi, lo;
    hi.x = f2bf(x.x); lo.x = f2bf(x.x - bf2f(hi.x));
    hi.y = f2bf(x.y); lo.y = f2bf(x.y - bf2f(hi.y));
    hi.z = f2bf(x.z); lo.z = f2bf(x.z - bf2f(hi.z));
    hi.w = f2bf(x.w); lo.w = f2bf(x.w - bf2f(hi.w));
    ((ushort4*)dh)[o] = hi;
    ((ushort4*)dl)[o] = lo;
}

// =====================================================================
// GEMM1 (MFMA): X f32 (in-register split) @ W^T (pre-split) + b -> LN
// z=0: Q*D^-0.5 -> split bf16 [bh][i][d]
// z=1: K        -> split bf16 [bh][i][d]
// z=2: V        -> split bf16 TRANSPOSED [bh][d][j]
// grid (32, 8, 3) block 256 (4 waves); wave: 32 rows x 64 cols.
// Epilogue stages the 128x64 tile in LDS -> fully coalesced stores.
// =====================================================================
__global__ __launch_bounds__(256, 4) void gemm_qkv_ln_mfma(
    const float* __restrict__ query, const float* __restrict__ key_in,
    const float* __restrict__ value,
    const u16* __restrict__ iwh, const u16* __restrict__ iwl,
    const float* __restrict__ ipb,
    u16* __restrict__ qhi, u16* __restrict__ qlo,
    u16* __restrict__ khi, u16* __restrict__ klo,
    u16* __restrict__ vth, u16* __restrict__ vtl)
{
    __shared__ float Et[8704];   // [128][68] f32 (z<2)  or  [64][133] (z==2)

    const int z = blockIdx.z;
    const float* Xf = (z == 0) ? query : (z == 1) ? key_in : value;
    const float scale = (z == 0) ? 0.125f : 1.0f;

    const int t0  = blockIdx.x * 128;
    const int h   = blockIdx.y;
    const int og0 = z * EMB + h * 64;

    const int tid = threadIdx.x;
    const int w   = tid >> 6;
    const int l   = tid & 63;
    const int c   = l & 15;
    const int g   = l >> 4;

    f32x4 acc[2][4];
#pragma unroll
    for (int mf = 0; mf < 2; ++mf)
#pragma unroll
        for (int nf = 0; nf < 4; ++nf) acc[mf][nf] = (f32x4){0.f, 0.f, 0.f, 0.f};

    const int arow0 = t0 + w * 32 + c;
#pragma unroll
    for (int ks = 0; ks < 16; ++ks) {
        const int k0 = ks * 32 + g * 8;
        bf16x8 ah[2], al[2], bh[4], bl[4];
#pragma unroll
        for (int mf = 0; mf < 2; ++mf)
            split8(&Xf[(size_t)(arow0 + mf * 16) * EMB + k0], ah[mf], al[mf]);
#pragma unroll
        for (int nf = 0; nf < 4; ++nf) {
            const size_t r = (size_t)(og0 + nf * 16 + c) * EMB + k0;
            bh[nf] = *(const bf16x8*)&iwh[r];
            bl[nf] = *(const bf16x8*)&iwl[r];
        }
#pragma unroll
        for (int mf = 0; mf < 2; ++mf)
#pragma unroll
            for (int nf = 0; nf < 4; ++nf) {
                f32x4 t = acc[mf][nf];
                t = __builtin_amdgcn_mfma_f32_16x16x32_bf16(ah[mf], bh[nf], t, 0, 0, 0);
                t = __builtin_amdgcn_mfma_f32_16x16x32_bf16(al[mf], bh[nf], t, 0, 0, 0);
                t = __builtin_amdgcn_mfma_f32_16x16x32_bf16(ah[mf], bl[nf], t, 0, 0, 0);
                acc[mf][nf] = t;
            }
    }

    // bias
#pragma unroll
    for (int nf = 0; nf < 4; ++nf) {
        const float bj = ipb[og0 + nf * 16 + c];
#pragma unroll
        for (int mf = 0; mf < 2; ++mf)
#pragma unroll
            for (int j = 0; j < 4; ++j) acc[mf][nf][j] += bj;
    }

    // LayerNorm per token row + stage to LDS
#pragma unroll
    for (int mf = 0; mf < 2; ++mf) {
        float mu[4], rs[4];
#pragma unroll
        for (int j = 0; j < 4; ++j) {
            float s = acc[mf][0][j] + acc[mf][1][j] + acc[mf][2][j] + acc[mf][3][j];
#pragma unroll
            for (int d = 1; d <= 8; d <<= 1) s += __shfl_xor(s, d);
            mu[j] = s * (1.0f / 64.0f);
        }
#pragma unroll
        for (int j = 0; j < 4; ++j) {
            float t = 0.f;
#pragma unroll
            for (int nf = 0; nf < 4; ++nf) {
                const float dv = acc[mf][nf][j] - mu[j];
                t += dv * dv;
            }
#pragma unroll
            for (int d = 1; d <= 8; d <<= 1) t += __shfl_xor(t, d);
            rs[j] = rsqrtf(t * (1.0f / 64.0f) + 1e-5f) * scale;
        }
#pragma unroll
        for (int j = 0; j < 4; ++j) {
            const int tl = w * 32 + mf * 16 + g * 4 + j;   // 0..127
#pragma unroll
            for (int nf = 0; nf < 4; ++nf) {
                const float val = (acc[mf][nf][j] - mu[j]) * rs[j];
                const int o = nf * 16 + c;                 // 0..63
                if (z == 2) Et[o * 133 + tl] = val;        // [d][tok]
                else        Et[tl * 68 + o]  = val;        // [tok][d]
            }
        }
    }
    __syncthreads();

    // coalesced store phase: 256 segments x 128 B, 8 threads per segment
    const int part = tid & 7;
    if (z < 2) {
        u16* dh = (z == 0) ? qhi : khi;
        u16* dl = (z == 0) ? qlo : klo;
#pragma unroll
        for (int p = 0; p < 8; ++p) {
            const int seg = p * 32 + (tid >> 3);
            const int tl  = seg & 127;
            const int hl  = seg >> 7;
            const float4 v0 = *(const float4*)&Et[tl * 68 + part * 8];
            const float4 v1 = *(const float4*)&Et[tl * 68 + part * 8 + 4];
            const float vv[8] = {v0.x, v0.y, v0.z, v0.w, v1.x, v1.y, v1.z, v1.w};
            unsigned pk[4];
#pragma unroll
            for (int q = 0; q < 4; ++q) {
                u16 ua, ub;
                if (hl == 0) { ua = f2bf(vv[2*q]); ub = f2bf(vv[2*q+1]); }
                else {
                    const u16 ha = f2bf(vv[2*q]),  hb = f2bf(vv[2*q+1]);
                    ua = f2bf(vv[2*q] - bf2f(ha)); ub = f2bf(vv[2*q+1] - bf2f(hb));
                }
                pk[q] = (unsigned)ua | ((unsigned)ub << 16);
            }
            const int bh_ = (tl & 1) * NH + h;
            const int ii  = (t0 >> 1) + (tl >> 1);
            u16* dst = hl ? dl : dh;
            *(uint4*)&dst[((size_t)bh_ * SEQ + ii) * 64 + part * 8] =
                make_uint4(pk[0], pk[1], pk[2], pk[3]);
        }
    } else {
#pragma unroll
        for (int p = 0; p < 8; ++p) {
            const int seg  = p * 32 + (tid >> 3);
            const int d    = seg & 63;
            const int rest = seg >> 6;
            const int b    = rest & 1;
            const int hl   = rest >> 1;
            float vv[8];
#pragma unroll
            for (int k = 0; k < 8; ++k)
                vv[k] = Et[d * 133 + 2 * (part * 8 + k) + b];
            unsigned pk[4];
#pragma unroll
            for (int q = 0; q < 4; ++q) {
                u16 ua, ub;
                if (hl == 0) { ua = f2bf(vv[2*q]); ub = f2bf(vv[2*q+1]); }
                else {
                    const u16 ha = f2bf(vv[2*q]),  hb = f2bf(vv[2*q+1]);
                    ua = f2bf(vv[2*q] - bf2f(ha)); ub = f2bf(vv[2*q+1] - bf2f(hb));
                }
                pk[q] = (unsigned)ua | ((unsigned)ub << 16);
            }
            const int bh_ = b * NH + h;
            u16* dst = hl ? vtl : vth;
            *(uint4*)&dst[((size_t)bh_ * 64 + d) * SEQ + (t0 >> 1) + part * 8] =
                make_uint4(pk[0], pk[1], pk[2], pk[3]);
        }
    }
}

// =====================================================================
// Fused attention: 16 q-rows/block, 8 waves x 256-j each.
// Swapped QK^T (S^T) -> Michelot sparsemax (dbuf reduce, 1 barrier/iter)
// -> dense split-bf16 PV (wave-private LDS P-transpose) -> ds_add_f32
// cross-wave O reduce -> ao split bf16.
// Registers <=128 (acc[16]=64) -> 4 waves/SIMD -> 2 blocks/CU.
// grid 2048 (XCD-pinned)  block 512.
// =====================================================================
__global__ __launch_bounds__(512, 4) void attn_sparsemax_mfma(
    const u16* __restrict__ qhi, const u16* __restrict__ qlo,
    const u16* __restrict__ khi, const u16* __restrict__ klo,
    const u16* __restrict__ vth, const u16* __restrict__ vtl,
    u16* __restrict__ aoh, u16* __restrict__ aol)
{
    __shared__ u16   Pst[8][2][16][40];    // wave-private P^T staging (hi/lo)
    __shared__ float O_lds[16][67];        // cross-wave O accumulator (ds_add)
    __shared__ float wred[2][8][16];       // double-buffered Michelot reduce
    __shared__ float wcnt[2][8][16];

    const int tid = threadIdx.x;
    const int w   = tid >> 6;
    const int l   = tid & 63;
    const int c   = l & 15;
    const int g   = l >> 4;

    const int wgid = blockIdx.x;
    const int xcd  = wgid & 7;
    const int idx  = wgid >> 3;             // 0..255 XCD-local order
    const int bh   = xcd * 2 + (idx >> 7);  // one bh working set at a time
    const int q0   = (idx & 127) * 16;

    // zero O accumulator (barrier below makes it visible before any ds_add)
    for (int f = tid; f < 16 * 67; f += 512) ((float*)O_lds)[f] = 0.f;

    const size_t bhoff = (size_t)bh * SEQ * 64;
    const u16* qh  = qhi + bhoff;
    const u16* ql  = qlo + bhoff;
    const u16* kh  = khi + bhoff;
    const u16* kl  = klo + bhoff;
    const u16* vh_ = vth + bhoff;          // [64][2048]
    const u16* vl_ = vtl + bhoff;

    // Q B-fragments (rows q0..q0+15)
    bf16x8 qhf[2], qlf[2];
#pragma unroll
    for (int kf = 0; kf < 2; ++kf) {
        const size_t a = (size_t)(q0 + c) * 64 + kf * 32 + g * 8;
        qhf[kf] = *(const bf16x8*)&qh[a];
        qlf[kf] = *(const bf16x8*)&ql[a];
    }

    // S^T = K @ Q^T : lane (c,g) holds j = mf*16+g*4+r, i = c
    const int wbase = w * 256;
    f32x4 acc[16];
#pragma unroll
    for (int mf = 0; mf < 16; ++mf) {
        const size_t kr = (size_t)(wbase + mf * 16 + c) * 64 + g * 8;
        const bf16x8 kh0 = *(const bf16x8*)&kh[kr];
        const bf16x8 kh1 = *(const bf16x8*)&kh[kr + 32];
        const bf16x8 kl0 = *(const bf16x8*)&kl[kr];
        const bf16x8 kl1 = *(const bf16x8*)&kl[kr + 32];
        f32x4 t = (f32x4){0.f, 0.f, 0.f, 0.f};
        t = __builtin_amdgcn_mfma_f32_16x16x32_bf16(kh0, qhf[0], t, 0, 0, 0);
        t = __builtin_amdgcn_mfma_f32_16x16x32_bf16(kh1, qhf[1], t, 0, 0, 0);
        t = __builtin_amdgcn_mfma_f32_16x16x32_bf16(kl0, qhf[0], t, 0, 0, 0);
        t = __builtin_amdgcn_mfma_f32_16x16x32_bf16(kl1, qhf[1], t, 0, 0, 0);
        t = __builtin_amdgcn_mfma_f32_16x16x32_bf16(kh0, qlf[0], t, 0, 0, 0);
        t = __builtin_amdgcn_mfma_f32_16x16x32_bf16(kh1, qlf[1], t, 0, 0, 0);
        acc[mf] = t;
    }

    // row max (row i = c) -> wred[0]
    {
        float m = -1e30f;
#pragma unroll
        for (int mf = 0; mf < 16; ++mf)
#pragma unroll
            for (int r = 0; r < 4; ++r) m = fmaxf(m, acc[mf][r]);
        m = fmaxf(m, __shfl_xor(m, 16));
        m = fmaxf(m, __shfl_xor(m, 32));
        if (g == 0) wred[0][w][c] = m;
    }
    __syncthreads();

    float tau;
    {
        float m = -1e30f;
#pragma unroll
        for (int ww = 0; ww < 8; ++ww) m = fmaxf(m, wred[0][ww][c]);
        tau = m - 1.0f;                 // tau* >= max-1
    }

    // Michelot fixed point: 1 barrier/iter, double-buffered
    int cprev = -1;
    for (int it = 0; it < 24; ++it) {
        const int bs = (~it) & 1;       // 1,0,1,0,...
        float s = 0.f, cn = 0.f;
#pragma unroll
        for (int mf = 0; mf < 16; ++mf)
#pragma unroll
            for (int r = 0; r < 4; ++r) {
                const float v = acc[mf][r];
                if (v > tau) { s += v; cn += 1.f; }
            }
        s  += __shfl_xor(s, 16);  cn += __shfl_xor(cn, 16);
        s  += __shfl_xor(s, 32);  cn += __shfl_xor(cn, 32);
        if (g == 0) { wred[bs][w][c] = s; wcnt[bs][w][c] = cn; }
        __syncthreads();
        float S = 0.f, C = 0.f;
#pragma unroll
        for (int ww = 0; ww < 8; ++ww) {
            S += wred[bs][ww][c];
            C += wcnt[bs][ww][c];
        }
        tau = (S - 1.0f) / C;
        const int Ci = (int)C;
        const int changed = (Ci != cprev);
        cprev = Ci;
        if (!__any(changed)) break;     // wave-uniform & identical across waves
    }

    // dense PV: O^T[d,i] = sum_j V^T[d,j] * P^T[j,i]
    f32x4 Oacc[4];
#pragma unroll
    for (int mo = 0; mo < 4; ++mo) Oacc[mo] = (f32x4){0.f, 0.f, 0.f, 0.f};

#pragma unroll
    for (int ks = 0; ks < 8; ++ks) {
        // P -> split bf16, staged via wave-private LDS transpose
#pragma unroll
        for (int m01 = 0; m01 < 2; ++m01) {
            const f32x4 s = acc[2 * ks + m01];
            const float p0 = fmaxf(s[0] - tau, 0.f);
            const float p1 = fmaxf(s[1] - tau, 0.f);
            const float p2 = fmaxf(s[2] - tau, 0.f);
            const float p3 = fmaxf(s[3] - tau, 0.f);
            const unsigned h0 = cvtpk(p0, p1);
            const unsigned h1 = cvtpk(p2, p3);
            const unsigned l0 = cvtpk(p0 - __uint_as_float(h0 << 16),
                                      p1 - __uint_as_float(h0 & 0xFFFF0000u));
            const unsigned l1 = cvtpk(p2 - __uint_as_float(h1 << 16),
                                      p3 - __uint_as_float(h1 & 0xFFFF0000u));
            *(u64*)&Pst[w][0][c][m01 * 16 + g * 4] = (u64)h0 | ((u64)h1 << 32);
            *(u64*)&Pst[w][1][c][m01 * 16 + g * 4] = (u64)l0 | ((u64)l1 << 32);
        }
        const bf16x8 Bhi = *(const bf16x8*)&Pst[w][0][c][g * 8];
        const bf16x8 Blo = *(const bf16x8*)&Pst[w][1][c][g * 8];
#pragma unroll
        for (int mo = 0; mo < 4; ++mo) {
            const size_t va = (size_t)(mo * 16 + c) * SEQ + wbase + ks * 32 + g * 8;
            const bf16x8 vh = *(const bf16x8*)&vh_[va];
            const bf16x8 vl = *(const bf16x8*)&vl_[va];
            f32x4 t = Oacc[mo];
            t = __builtin_amdgcn_mfma_f32_16x16x32_bf16(vh, Bhi, t, 0, 0, 0);
            t = __builtin_amdgcn_mfma_f32_16x16x32_bf16(vh, Blo, t, 0, 0, 0);
            t = __builtin_amdgcn_mfma_f32_16x16x32_bf16(vl, Bhi, t, 0, 0, 0);
            Oacc[mo] = t;
        }
    }

    // cross-wave reduce via LDS float atomics (intra-wave addrs distinct)
#pragma unroll
    for (int mo = 0; mo < 4; ++mo)
#pragma unroll
        for (int r = 0; r < 4; ++r)
            atomicAdd(&O_lds[c][mo * 16 + g * 4 + r], Oacc[mo][r]);
    __syncthreads();

    // epilogue: 16 rows x 64 d
    const int b_ = bh >> 3, h_ = bh & 7;
#pragma unroll
    for (int p = 0; p < 2; ++p) {
        const int idx2 = p * 512 + tid;       // 0..1023
        const int d = idx2 & 63;
        const int i = idx2 >> 6;              // 0..15
        const float sv = O_lds[i][d];
        const int irow = q0 + i;
        const size_t oa = (size_t)(irow * BATCH + b_) * EMB + h_ * 64 + d;
        const u16 hv = f2bf(sv);
        aoh[oa] = hv;
        aol[oa] = f2bf(sv - bf2f(hv));
    }
}

// =====================================================================
// GEMM2 (MFMA, split): ao @ opw^T + opb -> d_out f32. grid (32,8) blk 256.
// LDS-staged coalesced epilogue.
// =====================================================================
__global__ __launch_bounds__(256, 4) void gemm_out_mfma(
    const u16* __restrict__ aoh, const u16* __restrict__ aol,
    const u16* __restrict__ owh, const u16* __restrict__ owl,
    const float* __restrict__ opb, float* __restrict__ out)
{
    __shared__ float Et[128 * 68];

    const int t0 = blockIdx.x * 128;
    const int o0 = blockIdx.y * 64;

    const int tid = threadIdx.x;
    const int w   = tid >> 6;
    const int l   = tid & 63;
    const int c   = l & 15;
    const int g   = l >> 4;

    f32x4 acc[2][4];
#pragma unroll
    for (int mf = 0; mf < 2; ++mf)
#pragma unroll
        for (int nf = 0; nf < 4; ++nf) acc[mf][nf] = (f32x4){0.f, 0.f, 0.f, 0.f};

    const int arow0 = t0 + w * 32 + c;
#pragma unroll
    for (int ks = 0; ks < 16; ++ks) {
        const int k0 = ks * 32 + g * 8;
        bf16x8 ah[2], al[2], bh[4], bl[4];
#pragma unroll
        for (int mf = 0; mf < 2; ++mf) {
            const size_t r = (size_t)(arow0 + mf * 16) * EMB + k0;
            ah[mf] = *(const bf16x8*)&aoh[r];
            al[mf] = *(const bf16x8*)&aol[r];
        }
#pragma unroll
        for (int nf = 0; nf < 4; ++nf) {
            const size_t r = (size_t)(o0 + nf * 16 + c) * EMB + k0;
            bh[nf] = *(const bf16x8*)&owh[r];
            bl[nf] = *(const bf16x8*)&owl[r];
        }
#pragma unroll
        for (int mf = 0; mf < 2; ++mf)
#pragma unroll
            for (int nf = 0; nf < 4; ++nf) {
                f32x4 t = acc[mf][nf];
                t = __builtin_amdgcn_mfma_f32_16x16x32_bf16(ah[mf], bh[nf], t, 0, 0, 0);
                t = __builtin_amdgcn_mfma_f32_16x16x32_bf16(al[mf], bh[nf], t, 0, 0, 0);
                t = __builtin_amdgcn_mfma_f32_16x16x32_bf16(ah[mf], bl[nf], t, 0, 0, 0);
                acc[mf][nf] = t;
            }
    }

    // stage (+bias) to LDS
#pragma unroll
    for (int mf = 0; mf < 2; ++mf)
#pragma unroll
        for (int j = 0; j < 4; ++j) {
            const int tl = w * 32 + mf * 16 + g * 4 + j;
#pragma unroll
            for (int nf = 0; nf < 4; ++nf)
                Et[tl * 68 + nf * 16 + c] = acc[mf][nf][j] + opb[o0 + nf * 16 + c];
        }
    __syncthreads();

    // coalesced stores: 128 rows x 64 f32; 16 threads per row
    const int part = tid & 15;
#pragma unroll
    for (int p = 0; p < 8; ++p) {
        const int row = p * 16 + (tid >> 4);
        const float4 v = *(const float4*)&Et[row * 68 + part * 4];
        *(float4*)&out[(size_t)(t0 + row) * EMB + o0 + part * 4] = v;
    }
}

// =====================================================================
extern "C" void kernel_launch(void* const* d_in, const int* in_sizes, int n_in,
                              void* d_out, int out_size, void* d_ws, size_t ws_size,
                              hipStream_t stream)
{
    const float* query = (const float*)d_in[0];
    const float* key_  = (const float*)d_in[1];
    const float* value = (const float*)d_in[2];
    const float* ipw   = (const float*)d_in[3];
    const float* ipb   = (const float*)d_in[4];
    const float* opw   = (const float*)d_in[5];
    const float* opb   = (const float*)d_in[6];
    // d_in[7] = update_steps_max (0)

    char* ws = (char*)d_ws;
    const size_t MB = 1024 * 1024;
    u16* qhi = (u16*)(ws + 0 * MB);    // 4 MB each
    u16* qlo = (u16*)(ws + 4 * MB);
    u16* khi = (u16*)(ws + 8 * MB);
    u16* klo = (u16*)(ws + 12 * MB);
    u16* vth = (u16*)(ws + 16 * MB);   // transposed V [bh][64][2048]
    u16* vtl = (u16*)(ws + 20 * MB);
    u16* aoh = (u16*)(ws + 24 * MB);
    u16* aol = (u16*)(ws + 28 * MB);
    u16* iwh = (u16*)(ws + 32 * MB);
    u16* iwl = (u16*)(ws + 34 * MB);
    u16* owh = (u16*)(ws + 36 * MB);
    u16* owl = (u16*)(ws + 37 * MB);
    float* out = (float*)d_out;
    (void)ws_size; (void)in_sizes; (void)n_in; (void)out_size;

    convert_w<<<1024, 256, 0, stream>>>(ipw, opw, iwh, iwl, owh, owl);
    gemm_qkv_ln_mfma<<<dim3(32, 8, 3), 256, 0, stream>>>(
        query, key_, value, iwh, iwl, ipb, qhi, qlo, khi, klo, vth, vtl);
    attn_sparsemax_mfma<<<2048, 512, 0, stream>>>(
        qhi, qlo, khi, klo, vth, vtl, aoh, aol);
    gemm_out_mfma<<<dim3(32, 8), 256, 0, stream>>>(
        aoh, aol, owh, owl, opb, out);
}

// Round 8
// 445.134 us; speedup vs baseline: 1.1057x; 1.1057x over previous
//
#include <hip/hip_runtime.h>

#define SEQ   2048
#define BATCH 2
#define EMB   512
#define NH    8
#define CAP   160        // per-row candidate capacity; overflow -> block-wide fallback

typedef short bf16x8 __attribute__((ext_vector_type(8)));
typedef float f32x4  __attribute__((ext_vector_type(4)));
typedef unsigned short u16;
typedef unsigned long long u64;

static __device__ __forceinline__ u16 f2bf(float f) {
    unsigned u = __float_as_uint(f);
    return (u16)((u + 0x7FFF + ((u >> 16) & 1)) >> 16);   // rne
}
static __device__ __forceinline__ float bf2f(u16 h) {
    return __uint_as_float((unsigned)h << 16);
}
static __device__ __forceinline__ unsigned cvtpk(float a, float b) {
    unsigned r;
    asm("v_cvt_pk_bf16_f32 %0, %1, %2" : "=v"(r) : "v"(a), "v"(b));
    return r;   // low16 = bf16(a), high16 = bf16(b), rne
}
// split 8 consecutive f32 into hi/lo bf16x8
static __device__ __forceinline__ void split8(const float* p, bf16x8& hi, bf16x8& lo) {
    const float4 f0 = *(const float4*)p;
    const float4 f1 = *(const float4*)(p + 4);
    const float fv[8] = {f0.x, f0.y, f0.z, f0.w, f1.x, f1.y, f1.z, f1.w};
    union { unsigned w[4]; bf16x8 v; } H, L;
#pragma unroll
    for (int q = 0; q < 4; ++q) {
        const float a = fv[2 * q], b = fv[2 * q + 1];
        const unsigned h = cvtpk(a, b);
        const float la = a - __uint_as_float(h << 16);
        const float lb = b - __uint_as_float(h & 0xFFFF0000u);
        H.w[q] = h;
        L.w[q] = cvtpk(la, lb);
    }
    hi = H.v; lo = L.v;
}

// =====================================================================
// GEMM1 (MFMA): X f32 and W f32 both split in-register -> +b -> LN
// z=0: Q*D^-0.5 -> split bf16 [bh][i][d]
// z=1: K        -> split bf16 [bh][i][d]
// z=2: V        -> split bf16 TRANSPOSED [bh][d][j]
// grid (32, 8, 3) block 256 (4 waves); wave: 32 rows x 64 cols.
// =====================================================================
__global__ __launch_bounds__(256, 4) void gemm_qkv_ln_mfma(
    const float* __restrict__ query, const float* __restrict__ key_in,
    const float* __restrict__ value,
    const float* __restrict__ ipw, const float* __restrict__ ipb,
    u16* __restrict__ qhi, u16* __restrict__ qlo,
    u16* __restrict__ khi, u16* __restrict__ klo,
    u16* __restrict__ vth, u16* __restrict__ vtl)
{
    __shared__ float Et[8704];   // [128][68] f32 (z<2)  or  [64][133] (z==2)

    const int z = blockIdx.z;
    const float* Xf = (z == 0) ? query : (z == 1) ? key_in : value;
    const float scale = (z == 0) ? 0.125f : 1.0f;

    const int t0  = blockIdx.x * 128;
    const int h   = blockIdx.y;
    const int og0 = z * EMB + h * 64;

    const int tid = threadIdx.x;
    const int w   = tid >> 6;
    const int l   = tid & 63;
    const int c   = l & 15;
    const int g   = l >> 4;

    f32x4 acc[2][4];
#pragma unroll
    for (int mf = 0; mf < 2; ++mf)
#pragma unroll
        for (int nf = 0; nf < 4; ++nf) acc[mf][nf] = (f32x4){0.f, 0.f, 0.f, 0.f};

    const int arow0 = t0 + w * 32 + c;
#pragma unroll
    for (int ks = 0; ks < 16; ++ks) {
        const int k0 = ks * 32 + g * 8;
        bf16x8 ah[2], al[2], bh[4], bl[4];
#pragma unroll
        for (int mf = 0; mf < 2; ++mf)
            split8(&Xf[(size_t)(arow0 + mf * 16) * EMB + k0], ah[mf], al[mf]);
#pragma unroll
        for (int nf = 0; nf < 4; ++nf)
            split8(&ipw[(size_t)(og0 + nf * 16 + c) * EMB + k0], bh[nf], bl[nf]);
#pragma unroll
        for (int mf = 0; mf < 2; ++mf)
#pragma unroll
            for (int nf = 0; nf < 4; ++nf) {
                f32x4 t = acc[mf][nf];
                t = __builtin_amdgcn_mfma_f32_16x16x32_bf16(ah[mf], bh[nf], t, 0, 0, 0);
                t = __builtin_amdgcn_mfma_f32_16x16x32_bf16(al[mf], bh[nf], t, 0, 0, 0);
                t = __builtin_amdgcn_mfma_f32_16x16x32_bf16(ah[mf], bl[nf], t, 0, 0, 0);
                acc[mf][nf] = t;
            }
    }

    // bias
#pragma unroll
    for (int nf = 0; nf < 4; ++nf) {
        const float bj = ipb[og0 + nf * 16 + c];
#pragma unroll
        for (int mf = 0; mf < 2; ++mf)
#pragma unroll
            for (int j = 0; j < 4; ++j) acc[mf][nf][j] += bj;
    }

    // LayerNorm per token row + stage to LDS
#pragma unroll
    for (int mf = 0; mf < 2; ++mf) {
        float mu[4], rs[4];
#pragma unroll
        for (int j = 0; j < 4; ++j) {
            float s = acc[mf][0][j] + acc[mf][1][j] + acc[mf][2][j] + acc[mf][3][j];
#pragma unroll
            for (int d = 1; d <= 8; d <<= 1) s += __shfl_xor(s, d);
            mu[j] = s * (1.0f / 64.0f);
        }
#pragma unroll
        for (int j = 0; j < 4; ++j) {
            float t = 0.f;
#pragma unroll
            for (int nf = 0; nf < 4; ++nf) {
                const float dv = acc[mf][nf][j] - mu[j];
                t += dv * dv;
            }
#pragma unroll
            for (int d = 1; d <= 8; d <<= 1) t += __shfl_xor(t, d);
            rs[j] = rsqrtf(t * (1.0f / 64.0f) + 1e-5f) * scale;
        }
#pragma unroll
        for (int j = 0; j < 4; ++j) {
            const int tl = w * 32 + mf * 16 + g * 4 + j;   // 0..127
#pragma unroll
            for (int nf = 0; nf < 4; ++nf) {
                const float val = (acc[mf][nf][j] - mu[j]) * rs[j];
                const int o = nf * 16 + c;                 // 0..63
                if (z == 2) Et[o * 133 + tl] = val;        // [d][tok]
                else        Et[tl * 68 + o]  = val;        // [tok][d]
            }
        }
    }
    __syncthreads();

    // coalesced store phase: 256 segments x 128 B, 8 threads per segment
    const int part = tid & 7;
    if (z < 2) {
        u16* dh = (z == 0) ? qhi : khi;
        u16* dl = (z == 0) ? qlo : klo;
#pragma unroll
        for (int p = 0; p < 8; ++p) {
            const int seg = p * 32 + (tid >> 3);
            const int tl  = seg & 127;
            const int hl  = seg >> 7;
            const float4 v0 = *(const float4*)&Et[tl * 68 + part * 8];
            const float4 v1 = *(const float4*)&Et[tl * 68 + part * 8 + 4];
            const float vv[8] = {v0.x, v0.y, v0.z, v0.w, v1.x, v1.y, v1.z, v1.w};
            unsigned pk[4];
#pragma unroll
            for (int q = 0; q < 4; ++q) {
                u16 ua, ub;
                if (hl == 0) { ua = f2bf(vv[2*q]); ub = f2bf(vv[2*q+1]); }
                else {
                    const u16 ha = f2bf(vv[2*q]),  hb = f2bf(vv[2*q+1]);
                    ua = f2bf(vv[2*q] - bf2f(ha)); ub = f2bf(vv[2*q+1] - bf2f(hb));
                }
                pk[q] = (unsigned)ua | ((unsigned)ub << 16);
            }
            const int bh_ = (tl & 1) * NH + h;
            const int ii  = (t0 >> 1) + (tl >> 1);
            u16* dst = hl ? dl : dh;
            *(uint4*)&dst[((size_t)bh_ * SEQ + ii) * 64 + part * 8] =
                make_uint4(pk[0], pk[1], pk[2], pk[3]);
        }
    } else {
#pragma unroll
        for (int p = 0; p < 8; ++p) {
            const int seg  = p * 32 + (tid >> 3);
            const int d    = seg & 63;
            const int rest = seg >> 6;
            const int b    = rest & 1;
            const int hl   = rest >> 1;
            float vv[8];
#pragma unroll
            for (int k = 0; k < 8; ++k)
                vv[k] = Et[d * 133 + 2 * (part * 8 + k) + b];
            unsigned pk[4];
#pragma unroll
            for (int q = 0; q < 4; ++q) {
                u16 ua, ub;
                if (hl == 0) { ua = f2bf(vv[2*q]); ub = f2bf(vv[2*q+1]); }
                else {
                    const u16 ha = f2bf(vv[2*q]),  hb = f2bf(vv[2*q+1]);
                    ua = f2bf(vv[2*q] - bf2f(ha)); ub = f2bf(vv[2*q+1] - bf2f(hb));
                }
                pk[q] = (unsigned)ua | ((unsigned)ub << 16);
            }
            const int bh_ = b * NH + h;
            u16* dst = hl ? vtl : vth;
            *(uint4*)&dst[((size_t)bh_ * 64 + d) * SEQ + (t0 >> 1) + part * 8] =
                make_uint4(pk[0], pk[1], pk[2], pk[3]);
        }
    }
}

// =====================================================================
// Fused attention: 32 q-rows/block (r6 shape), 8 waves x 256-j.
// Swapped QK^T -> candidate compaction (support subset of {z > max-1})
// -> per-wave barrier-free Michelot on compacted lists (block-wide
// fallback if any row > CAP) -> dense split-bf16 PV -> ds atomic O.
// grid 1024 (XCD-pinned)  block 512.
// =====================================================================
__global__ __launch_bounds__(512, 2) void attn_sparsemax_mfma(
    const u16* __restrict__ qhi, const u16* __restrict__ qlo,
    const u16* __restrict__ khi, const u16* __restrict__ klo,
    const u16* __restrict__ vth, const u16* __restrict__ vtl,
    u16* __restrict__ aoh, u16* __restrict__ aol)
{
    __shared__ u16   Pst[8][2][16][40];    // wave-private P^T staging (hi/lo)
    __shared__ float O_lds[32][67];        // cross-wave O accumulator (ds_add)
    __shared__ float clist[32][CAP];       // compacted candidates per row
    __shared__ int   ccnt[32];
    __shared__ float taus[32];
    __shared__ float wred[2][8][32];       // rowmax + fallback reduce (dbuf)
    __shared__ float wcnt_s[2][8][32];
    __shared__ int   oflow;

    const int tid = threadIdx.x;
    const int w   = tid >> 6;
    const int l   = tid & 63;
    const int c   = l & 15;
    const int g   = l >> 4;

    const int wgid = blockIdx.x;
    const int xcd  = wgid & 7;
    const int idx  = wgid >> 3;            // 0..127 XCD-local order
    const int bh   = xcd * 2 + (idx >> 6); // one bh working set at a time
    const int q0   = (idx & 63) * 32;

    for (int f = tid; f < 32 * 67; f += 512) ((float*)O_lds)[f] = 0.f;
    if (tid < 32) ccnt[tid] = 0;
    if (tid == 0) oflow = 0;

    const size_t bhoff = (size_t)bh * SEQ * 64;
    const u16* qh  = qhi + bhoff;
    const u16* ql  = qlo + bhoff;
    const u16* kh  = khi + bhoff;
    const u16* kl  = klo + bhoff;
    const u16* vh_ = vth + bhoff;          // [64][2048]
    const u16* vl_ = vtl + bhoff;

    // Q B-fragments
    bf16x8 qhf[2][2], qlf[2][2];
#pragma unroll
    for (int nf = 0; nf < 2; ++nf)
#pragma unroll
        for (int kf = 0; kf < 2; ++kf) {
            const size_t a = (size_t)(q0 + nf * 16 + c) * 64 + kf * 32 + g * 8;
            qhf[nf][kf] = *(const bf16x8*)&qh[a];
            qlf[nf][kf] = *(const bf16x8*)&ql[a];
        }

    // S^T = K @ Q^T : lane (c,g) holds rows i = nf*16+c, j = mf*16+g*4+r
    const int wbase = w * 256;
    f32x4 acc[16][2];
#pragma unroll
    for (int mf = 0; mf < 16; ++mf) {
        const size_t kr = (size_t)(wbase + mf * 16 + c) * 64 + g * 8;
        const bf16x8 kh0 = *(const bf16x8*)&kh[kr];
        const bf16x8 kh1 = *(const bf16x8*)&kh[kr + 32];
        const bf16x8 kl0 = *(const bf16x8*)&kl[kr];
        const bf16x8 kl1 = *(const bf16x8*)&kl[kr + 32];
#pragma unroll
        for (int nf = 0; nf < 2; ++nf) {
            f32x4 t = (f32x4){0.f, 0.f, 0.f, 0.f};
            t = __builtin_amdgcn_mfma_f32_16x16x32_bf16(kh0, qhf[nf][0], t, 0, 0, 0);
            t = __builtin_amdgcn_mfma_f32_16x16x32_bf16(kh1, qhf[nf][1], t, 0, 0, 0);
            t = __builtin_amdgcn_mfma_f32_16x16x32_bf16(kl0, qhf[nf][0], t, 0, 0, 0);
            t = __builtin_amdgcn_mfma_f32_16x16x32_bf16(kl1, qhf[nf][1], t, 0, 0, 0);
            t = __builtin_amdgcn_mfma_f32_16x16x32_bf16(kh0, qlf[nf][0], t, 0, 0, 0);
            t = __builtin_amdgcn_mfma_f32_16x16x32_bf16(kh1, qlf[nf][1], t, 0, 0, 0);
            acc[mf][nf] = t;
        }
    }

    // row max -> wred[0]
    {
        float mx[2];
#pragma unroll
        for (int nf = 0; nf < 2; ++nf) {
            float m = -1e30f;
#pragma unroll
            for (int mf = 0; mf < 16; ++mf)
#pragma unroll
                for (int r = 0; r < 4; ++r) m = fmaxf(m, acc[mf][nf][r]);
            m = fmaxf(m, __shfl_xor(m, 16));
            m = fmaxf(m, __shfl_xor(m, 32));
            mx[nf] = m;
        }
        if (g == 0) { wred[0][w][c] = mx[0]; wred[0][w][16 + c] = mx[1]; }
    }
    __syncthreads();     // also publishes O_lds/ccnt zeroing

    float tau0[2];
#pragma unroll
    for (int nf = 0; nf < 2; ++nf) {
        float m = -1e30f;
#pragma unroll
        for (int ww = 0; ww < 8; ++ww) m = fmaxf(m, wred[0][ww][nf * 16 + c]);
        tau0[nf] = m - 1.0f;            // tau* >= max-1 -> candidate threshold
    }

    // ---- candidate extraction (support subset of {z > tau0}) ----
#pragma unroll
    for (int nf = 0; nf < 2; ++nf) {
        const int row = nf * 16 + c;
#pragma unroll
        for (int mf = 0; mf < 16; ++mf)
#pragma unroll
            for (int r = 0; r < 4; ++r) {
                const float v = acc[mf][nf][r];
                if (v > tau0[nf]) {
                    const int pos = atomicAdd(&ccnt[row], 1);
                    if (pos < CAP) clist[row][pos] = v;
                    else           oflow = 1;
                }
            }
    }
    __syncthreads();

    float tau[2];
    if (oflow) {
        // -------- block-wide fallback (r6 path), rare/never --------
        tau[0] = tau0[0]; tau[1] = tau0[1];
        int cprev[2] = {-1, -1};
        for (int it = 0; it < 24; ++it) {
            const int bs = (~it) & 1;
            float sj[2], cj[2];
#pragma unroll
            for (int nf = 0; nf < 2; ++nf) {
                float s = 0.f, cn = 0.f;
#pragma unroll
                for (int mf = 0; mf < 16; ++mf)
#pragma unroll
                    for (int r = 0; r < 4; ++r) {
                        const float v = acc[mf][nf][r];
                        if (v > tau[nf]) { s += v; cn += 1.f; }
                    }
                s  += __shfl_xor(s, 16);  cn += __shfl_xor(cn, 16);
                s  += __shfl_xor(s, 32);  cn += __shfl_xor(cn, 32);
                sj[nf] = s; cj[nf] = cn;
            }
            if (g == 0) {
#pragma unroll
                for (int nf = 0; nf < 2; ++nf) {
                    wred[bs][w][nf * 16 + c]  = sj[nf];
                    wcnt_s[bs][w][nf * 16 + c] = cj[nf];
                }
            }
            __syncthreads();
            int changed = 0;
#pragma unroll
            for (int nf = 0; nf < 2; ++nf) {
                float S = 0.f, C = 0.f;
#pragma unroll
                for (int ww = 0; ww < 8; ++ww) {
                    S += wred[bs][ww][nf * 16 + c];
                    C += wcnt_s[bs][ww][nf * 16 + c];
                }
                tau[nf] = (S - 1.0f) / C;
                const int Ci = (int)C;
                changed |= (Ci != cprev[nf]);
                cprev[nf] = Ci;
            }
            if (!__any(changed)) break;
        }
    } else {
        // -------- per-wave barrier-free Michelot on compacted lists --------
#pragma unroll 1
        for (int rr = 0; rr < 4; ++rr) {
            const int i = w * 4 + rr;
            const int n = ccnt[i];
            float t0r = -1e30f;
#pragma unroll
            for (int ww = 0; ww < 8; ++ww) t0r = fmaxf(t0r, wred[0][ww][i]);
            t0r -= 1.0f;
            const float v0 = (l       < n) ? clist[i][l]       : -1e30f;
            const float v1 = (l + 64  < n) ? clist[i][l + 64]  : -1e30f;
            const float v2 = (l + 128 < n) ? clist[i][l + 128] : -1e30f;
            float tw = t0r;
            int cp = -1;
#pragma unroll 1
            for (int it = 0; it < 24; ++it) {
                float s = 0.f, cn = 0.f;
                if (v0 > tw) { s += v0; cn += 1.f; }
                if (v1 > tw) { s += v1; cn += 1.f; }
                if (v2 > tw) { s += v2; cn += 1.f; }
#pragma unroll
                for (int d = 1; d <= 32; d <<= 1) {
                    s  += __shfl_xor(s, d);
                    cn += __shfl_xor(cn, d);
                }
                tw = (s - 1.0f) / cn;
                const int ci = (int)cn;
                if (ci == cp) break;
                cp = ci;
            }
            if (l == 0) taus[i] = tw;
        }
        __syncthreads();
        tau[0] = taus[c];
        tau[1] = taus[16 + c];
    }

    // dense PV: O^T[d,i] = sum_j V^T[d,j] * P^T[j,i]
    f32x4 Oacc[4][2];
#pragma unroll
    for (int mo = 0; mo < 4; ++mo)
#pragma unroll
        for (int nf = 0; nf < 2; ++nf) Oacc[mo][nf] = (f32x4){0.f, 0.f, 0.f, 0.f};

#pragma unroll
    for (int ks = 0; ks < 8; ++ks) {
        bf16x8 vh[4], vl[4];
#pragma unroll
        for (int mo = 0; mo < 4; ++mo) {
            const size_t va = (size_t)(mo * 16 + c) * SEQ + wbase + ks * 32 + g * 8;
            vh[mo] = *(const bf16x8*)&vh_[va];
            vl[mo] = *(const bf16x8*)&vl_[va];
        }
#pragma unroll
        for (int nf = 0; nf < 2; ++nf) {
#pragma unroll
            for (int m01 = 0; m01 < 2; ++m01) {
                const f32x4 s = acc[2 * ks + m01][nf];
                const float p0 = fmaxf(s[0] - tau[nf], 0.f);
                const float p1 = fmaxf(s[1] - tau[nf], 0.f);
                const float p2 = fmaxf(s[2] - tau[nf], 0.f);
                const float p3 = fmaxf(s[3] - tau[nf], 0.f);
                const unsigned h0 = cvtpk(p0, p1);
                const unsigned h1 = cvtpk(p2, p3);
                const unsigned l0 = cvtpk(p0 - __uint_as_float(h0 << 16),
                                          p1 - __uint_as_float(h0 & 0xFFFF0000u));
                const unsigned l1 = cvtpk(p2 - __uint_as_float(h1 << 16),
                                          p3 - __uint_as_float(h1 & 0xFFFF0000u));
                *(u64*)&Pst[w][0][c][m01 * 16 + g * 4] = (u64)h0 | ((u64)h1 << 32);
                *(u64*)&Pst[w][1][c][m01 * 16 + g * 4] = (u64)l0 | ((u64)l1 << 32);
            }
            const bf16x8 Bhi = *(const bf16x8*)&Pst[w][0][c][g * 8];
            const bf16x8 Blo = *(const bf16x8*)&Pst[w][1][c][g * 8];
#pragma unroll
            for (int mo = 0; mo < 4; ++mo) {
                f32x4 t = Oacc[mo][nf];
                t = __builtin_amdgcn_mfma_f32_16x16x32_bf16(vh[mo], Bhi, t, 0, 0, 0);
                t = __builtin_amdgcn_mfma_f32_16x16x32_bf16(vh[mo], Blo, t, 0, 0, 0);
                t = __builtin_amdgcn_mfma_f32_16x16x32_bf16(vl[mo], Bhi, t, 0, 0, 0);
                Oacc[mo][nf] = t;
            }
        }
    }

    // cross-wave reduce via LDS float atomics
#pragma unroll
    for (int nf = 0; nf < 2; ++nf)
#pragma unroll
        for (int mo = 0; mo < 4; ++mo)
#pragma unroll
            for (int r = 0; r < 4; ++r)
                atomicAdd(&O_lds[nf * 16 + c][mo * 16 + g * 4 + r], Oacc[mo][nf][r]);
    __syncthreads();

    // epilogue: 32 rows x 64 d
    const int b_ = bh >> 3, h_ = bh & 7;
#pragma unroll
    for (int p = 0; p < 4; ++p) {
        const int idx2 = p * 512 + tid;       // 0..2047
        const int d = idx2 & 63;
        const int i = idx2 >> 6;              // 0..31
        const float sv = O_lds[i][d];
        const int irow = q0 + i;
        const size_t oa = (size_t)(irow * BATCH + b_) * EMB + h_ * 64 + d;
        const u16 hv = f2bf(sv);
        aoh[oa] = hv;
        aol[oa] = f2bf(sv - bf2f(hv));
    }
}

// =====================================================================
// GEMM2 (MFMA): ao (split bf16) @ opw^T (f32, in-register split) + opb
// -> d_out f32. grid (32,8) blk 256. LDS-staged coalesced epilogue.
// =====================================================================
__global__ __launch_bounds__(256, 4) void gemm_out_mfma(
    const u16* __restrict__ aoh, const u16* __restrict__ aol,
    const float* __restrict__ opw, const float* __restrict__ opb,
    float* __restrict__ out)
{
    __shared__ float Et[128 * 68];

    const int t0 = blockIdx.x * 128;
    const int o0 = blockIdx.y * 64;

    const int tid = threadIdx.x;
    const int w   = tid >> 6;
    const int l   = tid & 63;
    const int c   = l & 15;
    const int g   = l >> 4;

    f32x4 acc[2][4];
#pragma unroll
    for (int mf = 0; mf < 2; ++mf)
#pragma unroll
        for (int nf = 0; nf < 4; ++nf) acc[mf][nf] = (f32x4){0.f, 0.f, 0.f, 0.f};

    const int arow0 = t0 + w * 32 + c;
#pragma unroll
    for (int ks = 0; ks < 16; ++ks) {
        const int k0 = ks * 32 + g * 8;
        bf16x8 ah[2], al[2], bh[4], bl[4];
#pragma unroll
        for (int mf = 0; mf < 2; ++mf) {
            const size_t r = (size_t)(arow0 + mf * 16) * EMB + k0;
            ah[mf] = *(const bf16x8*)&aoh[r];
            al[mf] = *(const bf16x8*)&aol[r];
        }
#pragma unroll
        for (int nf = 0; nf < 4; ++nf)
            split8(&opw[(size_t)(o0 + nf * 16 + c) * EMB + k0], bh[nf], bl[nf]);
#pragma unroll
        for (int mf = 0; mf < 2; ++mf)
#pragma unroll
            for (int nf = 0; nf < 4; ++nf) {
                f32x4 t = acc[mf][nf];
                t = __builtin_amdgcn_mfma_f32_16x16x32_bf16(ah[mf], bh[nf], t, 0, 0, 0);
                t = __builtin_amdgcn_mfma_f32_16x16x32_bf16(al[mf], bh[nf], t, 0, 0, 0);
                t = __builtin_amdgcn_mfma_f32_16x16x32_bf16(ah[mf], bl[nf], t, 0, 0, 0);
                acc[mf][nf] = t;
            }
    }

    // stage (+bias) to LDS
#pragma unroll
    for (int mf = 0; mf < 2; ++mf)
#pragma unroll
        for (int j = 0; j < 4; ++j) {
            const int tl = w * 32 + mf * 16 + g * 4 + j;
#pragma unroll
            for (int nf = 0; nf < 4; ++nf)
                Et[tl * 68 + nf * 16 + c] = acc[mf][nf][j] + opb[o0 + nf * 16 + c];
        }
    __syncthreads();

    // coalesced stores: 128 rows x 64 f32; 16 threads per row
    const int part = tid & 15;
#pragma unroll
    for (int p = 0; p < 8; ++p) {
        const int row = p * 16 + (tid >> 4);
        const float4 v = *(const float4*)&Et[row * 68 + part * 4];
        *(float4*)&out[(size_t)(t0 + row) * EMB + o0 + part * 4] = v;
    }
}

// =====================================================================
extern "C" void kernel_launch(void* const* d_in, const int* in_sizes, int n_in,
                              void* d_out, int out_size, void* d_ws, size_t ws_size,
                              hipStream_t stream)
{
    const float* query = (const float*)d_in[0];
    const float* key_  = (const float*)d_in[1];
    const float* value = (const float*)d_in[2];
    const float* ipw   = (const float*)d_in[3];
    const float* ipb   = (const float*)d_in[4];
    const float* opw   = (const float*)d_in[5];
    const float* opb   = (const float*)d_in[6];
    // d_in[7] = update_steps_max (0)

    char* ws = (char*)d_ws;
    const size_t MB = 1024 * 1024;
    u16* qhi = (u16*)(ws + 0 * MB);    // 4 MB each
    u16* qlo = (u16*)(ws + 4 * MB);
    u16* khi = (u16*)(ws + 8 * MB);
    u16* klo = (u16*)(ws + 12 * MB);
    u16* vth = (u16*)(ws + 16 * MB);   // transposed V [bh][64][2048]
    u16* vtl = (u16*)(ws + 20 * MB);
    u16* aoh = (u16*)(ws + 24 * MB);
    u16* aol = (u16*)(ws + 28 * MB);
    float* out = (float*)d_out;
    (void)ws_size; (void)in_sizes; (void)n_in; (void)out_size;

    gemm_qkv_ln_mfma<<<dim3(32, 8, 3), 256, 0, stream>>>(
        query, key_, value, ipw, ipb, qhi, qlo, khi, klo, vth, vtl);
    attn_sparsemax_mfma<<<1024, 512, 0, stream>>>(
        qhi, qlo, khi, klo, vth, vtl, aoh, aol);
    gemm_out_mfma<<<dim3(32, 8), 256, 0, stream>>>(
        aoh, aol, opw, opb, out);
}